// Round 15
// baseline (74.150 us; speedup 1.0000x reference)
//
#include <hip/hip_runtime.h>
#include <stdint.h>

#define EPS 1e-5f
typedef unsigned long long u64;
typedef unsigned int u32;
typedef unsigned short u16;
typedef unsigned char u8;

// Precomputed constants living in d_ws, produced by prep_kernel each launch.
struct Consts {
  u32 p2r[16][4];   // conv2 +weight row masks: [ch][row r] = 24 bits (col*8+ci), [3]=pad
  u64 q3m0[32];     // conv3 +weight masks, taps 0..3 (bit t*16+ci)
  u64 q3m1[32];     // conv3 taps 4..7
  u32 q3m2[32];     // conv3 tap 8 (16 bits)
  int lo2[16];      // layer2: bit = (u32)(2ps-pc-lo2) <= rng2
  u32 rng2[16];
  float inv3[32];   // layer3 BN scale
  float A3[32];     // layer3 BN offset (beta - mean*inv)
  float b3v[32];    // conv3 bias
  float fcb[2];
  u8  lut[9 * 512]; // layer1: [borderType][pattern] -> 8 thresholded bits
};
static_assert(sizeof(Consts) == 6024, "layout");

// grid: block 0 = masks/thresholds; blocks 1..18 = 256 LUT entries each.
__global__ void prep_kernel(
    const float* __restrict__ w1, const float* __restrict__ b1,
    const float* __restrict__ g1, const float* __restrict__ be1,
    const float* __restrict__ m1, const float* __restrict__ v1,
    const float* __restrict__ w2, const float* __restrict__ b2,
    const float* __restrict__ g2, const float* __restrict__ be2,
    const float* __restrict__ m2, const float* __restrict__ v2,
    const float* __restrict__ w3, const float* __restrict__ b3,
    const float* __restrict__ g3, const float* __restrict__ be3,
    const float* __restrict__ m3, const float* __restrict__ v3,
    const float* __restrict__ fcb, Consts* __restrict__ out)
{
  int tid = threadIdx.x;

  if (blockIdx.x == 0) {
    // ---- layer 2: weight row masks + integer threshold range ----
    if (tid < 16) {
      int c = tid;
      u32 rm[3] = {0u, 0u, 0u};
      for (int ci = 0; ci < 8; ++ci)
        for (int t = 0; t < 9; ++t) {
          float w = w2[(c * 8 + ci) * 9 + t];
          if (w > 0.f) rm[t / 3] |= 1u << ((t % 3) * 8 + ci);
        }
      out->p2r[c][0] = rm[0]; out->p2r[c][1] = rm[1];
      out->p2r[c][2] = rm[2]; out->p2r[c][3] = 0u;
      float inv = __fdiv_rn(g2[c], __fsqrt_rn(__fadd_rn(v2[c], EPS)));
      float A   = __fsub_rn(be2[c], __fmul_rn(m2[c], inv));
      int lo = 1000, hi = -1000;
      for (int s = -72; s <= 72; ++s) {
        float y  = __fadd_rn((float)s, b2[c]);
        float bn = __fadd_rn(__fmul_rn(y, inv), A);
        if (bn > 0.f) { if (s < lo) lo = s; if (s > hi) hi = s; }
      }
      out->lo2[c] = lo; out->rng2[c] = (u32)(hi - lo);
    }
    // ---- layer 3: weight masks + BN params ----
    if (tid < 32) {
      int c = tid;
      u64 q0 = 0, q1 = 0; u32 q2 = 0;
      for (int ci = 0; ci < 16; ++ci)
        for (int t = 0; t < 9; ++t) {
          float w = w3[(c * 16 + ci) * 9 + t];
          if (w > 0.f) {
            if (t < 4)      q0 |= 1ull << (t * 16 + ci);
            else if (t < 8) q1 |= 1ull << ((t - 4) * 16 + ci);
            else            q2 |= 1u << ci;
          }
        }
      out->q3m0[c] = q0; out->q3m1[c] = q1; out->q3m2[c] = q2;
      float inv = __fdiv_rn(g3[c], __fsqrt_rn(__fadd_rn(v3[c], EPS)));
      out->inv3[c] = inv;
      out->A3[c]   = __fsub_rn(be3[c], __fmul_rn(m3[c], inv));
      out->b3v[c]  = b3[c];
    }
    if (tid < 2) out->fcb[tid] = fcb[tid];
    return;
  }

  // ---- layer 1 LUT: one entry per thread ----
  __shared__ float inv1s[8], A1s[8];
  __shared__ int   sw1[8][9];
  if (tid < 8) {
    int c = tid;
    float inv = __fdiv_rn(g1[c], __fsqrt_rn(__fadd_rn(v1[c], EPS)));
    inv1s[c] = inv;
    A1s[c]   = __fsub_rn(be1[c], __fmul_rn(m1[c], inv));
    for (int t = 0; t < 9; ++t) sw1[c][t] = (w1[c * 9 + t] > 0.f) ? 1 : -1;
  }
  __syncthreads();
  int e = (blockIdx.x - 1) * 256 + tid;  // 18*256 = 4608 entries
  int type = e >> 9, pat = e & 511;
  int ty = type / 3, tx = type % 3; // 0: low-edge OOB, 2: high-edge OOB, 1: interior
  u8 byte = 0;
  for (int c = 0; c < 8; ++c) {
    int s = 0;
    for (int t = 0; t < 9; ++t) {
      int dr = t / 3, dc = t % 3;
      bool valid = !((ty == 0 && dr == 0) || (ty == 2 && dr == 2) ||
                     (tx == 0 && dc == 0) || (tx == 2 && dc == 2));
      if (!valid) continue;
      s += ((pat >> t) & 1) ? sw1[c][t] : -sw1[c][t];
    }
    float y  = __fadd_rn((float)s, b1[c]);
    float bn = __fadd_rn(__fmul_rn(y, inv1s[c]), A1s[c]);
    if (bn > 0.f) byte |= (u8)(1u << c);
  }
  out->lut[e] = byte;
}

__launch_bounds__(128, 4)
__global__ void main_kernel(const float* __restrict__ x, const float* __restrict__ fcw,
                            const Consts* __restrict__ cs, float* __restrict__ out, int B)
{
  __shared__ __align__(16) u8  slut[9 * 512];
  __shared__ __align__(16) u64 xb[64];       // row bitmasks for this block's image
  __shared__ __align__(16) u8  s2p[34][36];  // pooled layer1 bits (8ch/byte), zero border
  __shared__ __align__(16) u16 s3p[18][18];  // pooled layer2 bits (16ch/u16), zero border
  __shared__ float red[2][2];

  const int tid = threadIdx.x;
  const int w = tid >> 6, lane = tid & 63;   // wave index (0..1), lane
  const int img = blockIdx.x;

  // shared LUT copy + zero the padded intermediates
  for (int i = tid; i < 1152; i += 128) ((u32*)slut)[i] = ((const u32*)cs->lut)[i];
  for (int i = tid; i < 306; i += 128) ((u32*)s2p)[i] = 0;
  for (int i = tid; i < 162; i += 128) ((u32*)s3p)[i] = 0;

  // ---- stage A: prefetch all 32 x-values, then ballot chain (pure VALU) ----
  {
    const float* xp = x + (size_t)img * 4096 + (size_t)w * 2048;
    float xv[32];
    #pragma unroll
    for (int rr = 0; rr < 32; ++rr) xv[rr] = xp[rr * 64 + lane];
    u64 my = 0;
    #pragma unroll
    for (int rr = 0; rr < 32; ++rr) {
      u64 m = __ballot(xv[rr] > 0.f);
      if (lane == rr) my = m;
    }
    if (lane < 32) xb[w * 32 + lane] = my;
  }
  __syncthreads();

  // ---- stage B: conv1 via LUT (+BN threshold) + OR-pool -> s2p ----
  // De-diverged column handling: uniform per-lane shift/mask constants.
  {
    const int c = lane & 31, h = lane >> 5;
    const int j0 = 2 * c;
    const u32 sa0  = (c == 0) ? 0u : (u32)(j0 - 1);
    const u32 msk0 = (c == 0) ? 3u : 7u;
    const u32 sft0 = (c == 0) ? 1u : 0u;
    const u32 base0 = ((c == 0) ? 0u : 1u) << 9;   // tj0 << 9
    const u32 base1 = ((c == 31) ? 2u : 1u) << 9;  // tj1 << 9
    #pragma unroll
    for (int p = 0; p < 8; ++p) {
      const int pr = w * 16 + h * 8 + p;
      const int i0 = 2 * pr;
      u64 r0 = (i0 > 0) ? xb[i0 - 1] : 0ull;
      u64 r1 = xb[i0];
      u64 r2 = xb[i0 + 1];
      u64 r3 = (i0 + 2 < 64) ? xb[i0 + 2] : 0ull;
      u32 acc = 0;
      #pragma unroll
      for (int a = 0; a < 2; ++a) {
        u64 ra = a ? r1 : r0, rb = a ? r2 : r1, rc = a ? r3 : r2;
        const int i = i0 + a;
        const u32 ti9 = ((i == 0) ? 0u : ((i == 63) ? 6u : 3u)) << 9;
        u32 ea = ((u32)(ra >> sa0) & msk0) << sft0;
        u32 eb = ((u32)(rb >> sa0) & msk0) << sft0;
        u32 ec = ((u32)(rc >> sa0) & msk0) << sft0;
        acc |= slut[ti9 + base0 + (ea | (eb << 3) | (ec << 6))];
        u32 fa = (u32)(ra >> j0) & 7u;
        u32 fb = (u32)(rb >> j0) & 7u;
        u32 fc = (u32)(rc >> j0) & 7u;
        acc |= slut[ti9 + base1 + (fa | (fb << 3) | (fc << 6))];
      }
      s2p[pr + 1][c + 1] = (u8)acc;
    }
  }
  __syncthreads();

  // ---- preload fcw for this wave's 16 channels (consumed in stage D);
  //      stage C's VALU work hides the load latency ----
  float fw0[16], fw1[16];
  #pragma unroll
  for (int cc = 0; cc < 16; ++cc) {
    const int f = ((16 * w + cc) << 6) + lane;
    fw0[cc] = fcw[f];
    fw1[cc] = fcw[2048 + f];
  }

  // ---- stage C: conv2 via popcount + int threshold + OR-pool -> s3p ----
  // Each lane: one pooled-output PAIR (2 pooled cols) = 8 windows x 16 ch.
  // Channel-OUTER (unroll 1): 5 SGPR consts per iter, 8-window inner unrolled.
  {
    const int idx = w * 64 + lane;            // 0..127
    const int pi = idx >> 3, pjp = idx & 7;   // pooled row, pooled col-pair
    const int bo = 4 * pjp;                   // byte offset in padded row (4-aligned)
    const u32* rp0 = (const u32*)&s2p[2 * pi + 0][bo];
    const u32* rp1 = (const u32*)&s2p[2 * pi + 1][bo];
    const u32* rp2 = (const u32*)&s2p[2 * pi + 2][bo];
    const u32* rp3 = (const u32*)&s2p[2 * pi + 3][bo];
    u32 rl[4], rh[4];
    rl[0] = rp0[0]; rh[0] = rp0[1];
    rl[1] = rp1[0]; rh[1] = rp1[1];
    rl[2] = rp2[0]; rh[2] = rp2[1];
    rl[3] = rp3[0]; rh[3] = rp3[1];

    u32 d0[8], d1[8], d2[8]; int pc[8]; u32 cw[8];
    #pragma unroll
    for (int k = 0; k < 8; ++k) {
      const int o = k >> 2, a = (k >> 1) & 1, bb = k & 1;
      const int sh = 8 * (2 * o + bb);
      d0[k] = __builtin_amdgcn_alignbit(rh[a],     rl[a],     sh) & 0xFFFFFFu;
      d1[k] = __builtin_amdgcn_alignbit(rh[a + 1], rl[a + 1], sh) & 0xFFFFFFu;
      d2[k] = __builtin_amdgcn_alignbit(rh[a + 2], rl[a + 2], sh) & 0xFFFFFFu;
      pc[k] = __popc(d0[k]) + __popc(d1[k]) + __popc(d2[k]);
      cw[k] = 0u;
    }

    #pragma unroll 1
    for (int ch = 15; ch >= 0; --ch) {
      const u32 m0 = cs->p2r[ch][0];
      const u32 m1 = cs->p2r[ch][1];
      const u32 m2 = cs->p2r[ch][2];
      const int nlo = -cs->lo2[ch];
      const u32 rng = cs->rng2[ch];
      #pragma unroll
      for (int k = 0; k < 8; ++k) {
        int ps = __popc(d0[k] & m0) + __popc(d1[k] & m1) + __popc(d2[k] & m2);
        u32 t = (u32)(2 * ps - pc[k] + nlo);
        cw[k] = cw[k] + cw[k] + ((t <= rng) ? 1u : 0u);
      }
    }
    s3p[pi + 1][2 * pjp + 1] = (u16)(cw[0] | cw[1] | cw[2] | cw[3]);
    s3p[pi + 1][2 * pjp + 2] = (u16)(cw[4] | cw[5] | cw[6] | cw[7]);
  }
  __syncthreads();

  // ---- stage D: conv3 + BN/ReLU/pool (exact fp) + FC; wave w: ch 16w..16w+15 ----
  float l0 = 0.f, l1 = 0.f;
  {
    const int pi = lane >> 3, pj = lane & 7;
    const u32* p0 = (const u32*)(&s3p[2 * pi + 0][2 * pj]);
    const u32* p1 = (const u32*)(&s3p[2 * pi + 1][2 * pj]);
    const u32* p2 = (const u32*)(&s3p[2 * pi + 2][2 * pj]);
    const u32* p3 = (const u32*)(&s3p[2 * pi + 3][2 * pj]);
    const u64 rr0 = (u64)p0[0] | ((u64)p0[1] << 32);
    const u64 rr1 = (u64)p1[0] | ((u64)p1[1] << 32);
    const u64 rr2 = (u64)p2[0] | ((u64)p2[1] << 32);
    const u64 rr3 = (u64)p3[0] | ((u64)p3[1] << 32);

    u64 q0a, q1a, q0b, q1b, q0c, q1c, q0d, q1d;
    u32 q2a, q2b, q2c, q2d;
    int pca, pcb, pcc, pcd;
    {
      u64 ta, tb, tc;
      ta = rr0;       tb = rr1;       tc = rr2;
      q0a = (ta & 0xFFFFFFFFFFFFull) | ((tb & 0xFFFFull) << 48);
      q1a = ((tb >> 16) & 0xFFFFFFFFull) | ((tc & 0xFFFFFFFFull) << 32);
      q2a = (u32)((tc >> 32) & 0xFFFFull);
      pca = __popcll(q0a) + __popcll(q1a) + __popc(q2a);
      ta = rr0 >> 16; tb = rr1 >> 16; tc = rr2 >> 16;
      q0b = (ta & 0xFFFFFFFFFFFFull) | ((tb & 0xFFFFull) << 48);
      q1b = ((tb >> 16) & 0xFFFFFFFFull) | ((tc & 0xFFFFFFFFull) << 32);
      q2b = (u32)((tc >> 32) & 0xFFFFull);
      pcb = __popcll(q0b) + __popcll(q1b) + __popc(q2b);
      ta = rr1;       tb = rr2;       tc = rr3;
      q0c = (ta & 0xFFFFFFFFFFFFull) | ((tb & 0xFFFFull) << 48);
      q1c = ((tb >> 16) & 0xFFFFFFFFull) | ((tc & 0xFFFFFFFFull) << 32);
      q2c = (u32)((tc >> 32) & 0xFFFFull);
      pcc = __popcll(q0c) + __popcll(q1c) + __popc(q2c);
      ta = rr1 >> 16; tb = rr2 >> 16; tc = rr3 >> 16;
      q0d = (ta & 0xFFFFFFFFFFFFull) | ((tb & 0xFFFFull) << 48);
      q1d = ((tb >> 16) & 0xFFFFFFFFull) | ((tc & 0xFFFFFFFFull) << 32);
      q2d = (u32)((tc >> 32) & 0xFFFFull);
      pcd = __popcll(q0d) + __popcll(q1d) + __popc(q2d);
    }

    #pragma unroll 2
    for (int cc = 0; cc < 16; ++cc) {
      const int c = 16 * w + cc;
      const u64 m0 = cs->q3m0[c], m1 = cs->q3m1[c];
      const u32 m2 = cs->q3m2[c];
      int t0 = 2 * (__popcll(q0a & m0) + __popcll(q1a & m1) + __popc(q2a & m2)) - pca;
      int t1 = 2 * (__popcll(q0b & m0) + __popcll(q1b & m1) + __popc(q2b & m2)) - pcb;
      int t2 = 2 * (__popcll(q0c & m0) + __popcll(q1c & m1) + __popc(q2c & m2)) - pcc;
      int t3 = 2 * (__popcll(q0d & m0) + __popcll(q1d & m1) + __popc(q2d & m2)) - pcd;
      int smax = max(max(t0, t1), max(t2, t3));
      int smin = min(min(t0, t1), min(t2, t3));
      float inv = cs->inv3[c];
      int sel = (inv > 0.f) ? smax : smin;
      float y   = __fadd_rn((float)sel, cs->b3v[c]);
      float bn  = __fadd_rn(__fmul_rn(y, inv), cs->A3[c]);
      float val = fmaxf(bn, 0.f);
      l0 = fmaf(val, fw0[cc], l0);
      l1 = fmaf(val, fw1[cc], l1);
    }
  }

  // ---- reduce: per-wave shuffle, cross-wave via LDS, softmax ----
  #pragma unroll
  for (int d = 32; d >= 1; d >>= 1) {
    l0 += __shfl_xor(l0, d, 64);
    l1 += __shfl_xor(l1, d, 64);
  }
  if (lane == 0) { red[w][0] = l0; red[w][1] = l1; }
  __syncthreads();
  if (tid == 0) {
    float a0 = red[0][0] + red[1][0] + cs->fcb[0];
    float a1 = red[0][1] + red[1][1] + cs->fcb[1];
    float mm = fmaxf(a0, a1);
    float e0 = expf(a0 - mm), e1 = expf(a1 - mm);
    float sden = e0 + e1;
    out[(size_t)img * 2]     = e0 / sden;
    out[(size_t)img * 2 + 1] = e1 / sden;
  }
}

extern "C" void kernel_launch(void* const* d_in, const int* in_sizes, int n_in,
                              void* d_out, int out_size, void* d_ws, size_t ws_size,
                              hipStream_t stream) {
  const float* x   = (const float*)d_in[0];
  const float* w1  = (const float*)d_in[1];
  const float* b1  = (const float*)d_in[2];
  const float* g1  = (const float*)d_in[3];
  const float* be1 = (const float*)d_in[4];
  const float* m1  = (const float*)d_in[5];
  const float* v1  = (const float*)d_in[6];
  const float* w2  = (const float*)d_in[7];
  const float* b2  = (const float*)d_in[8];
  const float* g2  = (const float*)d_in[9];
  const float* be2 = (const float*)d_in[10];
  const float* m2  = (const float*)d_in[11];
  const float* v2  = (const float*)d_in[12];
  const float* w3  = (const float*)d_in[13];
  const float* b3  = (const float*)d_in[14];
  const float* g3  = (const float*)d_in[15];
  const float* be3 = (const float*)d_in[16];
  const float* m3  = (const float*)d_in[17];
  const float* v3  = (const float*)d_in[18];
  const float* fcw = (const float*)d_in[19];
  const float* fcb = (const float*)d_in[20];

  int B = in_sizes[0] / 4096;  // 64*64 per image
  Consts* cs = (Consts*)d_ws;

  prep_kernel<<<19, 256, 0, stream>>>(w1, b1, g1, be1, m1, v1,
                                      w2, b2, g2, be2, m2, v2,
                                      w3, b3, g3, be3, m3, v3, fcb, cs);
  main_kernel<<<B, 128, 0, stream>>>(x, fcw, cs, (float*)d_out, B);
}

// Round 16
// 67.479 us; speedup vs baseline: 1.0989x; 1.0989x over previous
//
#include <hip/hip_runtime.h>
#include <stdint.h>

#define EPS 1e-5f
typedef unsigned long long u64;
typedef unsigned int u32;
typedef unsigned short u16;
typedef unsigned char u8;

// Precomputed constants living in d_ws, produced by prep_kernel each launch.
struct Consts {
  u32 p2r[16][4];   // conv2 +weight row masks: [ch][row r] = 24 bits (col*8+ci), [3]=pad
  u64 q3m0[32];     // conv3 +weight masks, taps 0..3 (bit t*16+ci)
  u64 q3m1[32];     // conv3 taps 4..7
  u32 q3m2[32];     // conv3 tap 8 (16 bits)
  int lo2[16];      // layer2: bit = (u32)(2ps-pc-lo2) <= rng2
  u32 rng2[16];
  float inv3[32];   // layer3 BN scale
  float A3[32];     // layer3 BN offset (beta - mean*inv)
  float b3v[32];    // conv3 bias
  float fcb[2];
  u32 pad_[2];      // align lut to 16B
  u8  lut[9 * 4096]; // layer1 PAIR-LUT: [borderType][3rows x 4cols] ->
                     //  OR of the 2 horizontal windows' thresholded bytes
};
static_assert(sizeof(Consts) == 1424 + 9 * 4096, "layout");

// grid: block 0 = masks/thresholds; blocks 1..144 = 256 LUT entries each.
__global__ void prep_kernel(
    const float* __restrict__ w1, const float* __restrict__ b1,
    const float* __restrict__ g1, const float* __restrict__ be1,
    const float* __restrict__ m1, const float* __restrict__ v1,
    const float* __restrict__ w2, const float* __restrict__ b2,
    const float* __restrict__ g2, const float* __restrict__ be2,
    const float* __restrict__ m2, const float* __restrict__ v2,
    const float* __restrict__ w3, const float* __restrict__ b3,
    const float* __restrict__ g3, const float* __restrict__ be3,
    const float* __restrict__ m3, const float* __restrict__ v3,
    const float* __restrict__ fcb, Consts* __restrict__ out)
{
  int tid = threadIdx.x;

  if (blockIdx.x == 0) {
    // ---- layer 2: weight row masks + integer threshold range ----
    if (tid < 16) {
      int c = tid;
      u32 rm[3] = {0u, 0u, 0u};
      for (int ci = 0; ci < 8; ++ci)
        for (int t = 0; t < 9; ++t) {
          float w = w2[(c * 8 + ci) * 9 + t];
          if (w > 0.f) rm[t / 3] |= 1u << ((t % 3) * 8 + ci);
        }
      out->p2r[c][0] = rm[0]; out->p2r[c][1] = rm[1];
      out->p2r[c][2] = rm[2]; out->p2r[c][3] = 0u;
      float inv = __fdiv_rn(g2[c], __fsqrt_rn(__fadd_rn(v2[c], EPS)));
      float A   = __fsub_rn(be2[c], __fmul_rn(m2[c], inv));
      int lo = 1000, hi = -1000;
      for (int s = -72; s <= 72; ++s) {
        float y  = __fadd_rn((float)s, b2[c]);
        float bn = __fadd_rn(__fmul_rn(y, inv), A);
        if (bn > 0.f) { if (s < lo) lo = s; if (s > hi) hi = s; }
      }
      out->lo2[c] = lo; out->rng2[c] = (u32)(hi - lo);
    }
    // ---- layer 3: weight masks + BN params ----
    if (tid < 32) {
      int c = tid;
      u64 q0 = 0, q1 = 0; u32 q2 = 0;
      for (int ci = 0; ci < 16; ++ci)
        for (int t = 0; t < 9; ++t) {
          float w = w3[(c * 16 + ci) * 9 + t];
          if (w > 0.f) {
            if (t < 4)      q0 |= 1ull << (t * 16 + ci);
            else if (t < 8) q1 |= 1ull << ((t - 4) * 16 + ci);
            else            q2 |= 1u << ci;
          }
        }
      out->q3m0[c] = q0; out->q3m1[c] = q1; out->q3m2[c] = q2;
      float inv = __fdiv_rn(g3[c], __fsqrt_rn(__fadd_rn(v3[c], EPS)));
      out->inv3[c] = inv;
      out->A3[c]   = __fsub_rn(be3[c], __fmul_rn(m3[c], inv));
      out->b3v[c]  = b3[c];
    }
    if (tid < 2) out->fcb[tid] = fcb[tid];
    return;
  }

  // ---- layer 1 PAIR-LUT: one entry per thread ----
  // Entry: [type = ty*3+tx][12-bit pattern, bit dr*4+pc = row (i-1+dr), col (j0-1+pc)]
  // Value: OR over the two windows centered at cols j0, j0+1 of the
  //        thresholded 8-channel byte. OOB taps excluded (zero padding).
  __shared__ float inv1s[8], A1s[8];
  __shared__ int   sw1[8][9];
  if (tid < 8) {
    int c = tid;
    float inv = __fdiv_rn(g1[c], __fsqrt_rn(__fadd_rn(v1[c], EPS)));
    inv1s[c] = inv;
    A1s[c]   = __fsub_rn(be1[c], __fmul_rn(m1[c], inv));
    for (int t = 0; t < 9; ++t) sw1[c][t] = (w1[c * 9 + t] > 0.f) ? 1 : -1;
  }
  __syncthreads();
  int e = (blockIdx.x - 1) * 256 + tid;  // 144*256 = 36864 entries
  int type = e >> 12, pat = e & 4095;
  int ty = type / 3, tx = type % 3; // 0: low-edge OOB, 2: high-edge OOB, 1: interior
  u8 entry = 0;
  for (int wo = 0; wo < 2; ++wo) {
    u8 byte = 0;
    for (int c = 0; c < 8; ++c) {
      int s = 0;
      for (int dr = 0; dr < 3; ++dr) {
        if ((ty == 0 && dr == 0) || (ty == 2 && dr == 2)) continue;
        for (int dc = 0; dc < 3; ++dc) {
          int pc = wo + dc;  // pattern col; image col j0-1+pc
          if ((tx == 0 && pc == 0) || (tx == 2 && pc == 3)) continue;
          int bit = (pat >> (dr * 4 + pc)) & 1;
          s += bit ? sw1[c][dr * 3 + dc] : -sw1[c][dr * 3 + dc];
        }
      }
      float y  = __fadd_rn((float)s, b1[c]);
      float bn = __fadd_rn(__fmul_rn(y, inv1s[c]), A1s[c]);
      if (bn > 0.f) byte |= (u8)(1u << c);
    }
    entry |= byte;
  }
  out->lut[e] = entry;
}

__launch_bounds__(256, 4)
__global__ void main_kernel(const float* __restrict__ x, const float* __restrict__ fcw,
                            const Consts* __restrict__ cs, float* __restrict__ out, int B)
{
  __shared__ __align__(16) u8  slut[9 * 4096];
  __shared__ __align__(16) u64 xb[2][64];       // per-image row bitmasks
  __shared__ __align__(16) u8  s2p[2][34][36];  // pooled layer1 bits (8ch/byte), zero border
  __shared__ __align__(16) u16 s3p[2][18][18];  // pooled layer2 bits (16ch/u16), zero border
  __shared__ float red[2][2][2];

  const int tid = threadIdx.x;
  const int wv = tid >> 6, lane = tid & 63;
  const int im = wv >> 1, w = wv & 1;           // image slot, wave-within-image
  const int img = blockIdx.x * 2 + im;

  // shared LUT copy (uint4-vectorized) + zero the padded intermediates
  for (int i = tid; i < 2304; i += 256)
    ((uint4*)slut)[i] = ((const uint4*)cs->lut)[i];
  for (int i = tid; i < 612; i += 256) ((u32*)s2p)[i] = 0;
  for (int i = tid; i < 324; i += 256) ((u32*)s3p)[i] = 0;

  // ---- stage A: prefetch all 32 x-values, then ballot chain (pure VALU) ----
  if (img < B) {
    const float* xp = x + (size_t)img * 4096 + (size_t)w * 2048;
    float xv[32];
    #pragma unroll
    for (int rr = 0; rr < 32; ++rr) xv[rr] = xp[rr * 64 + lane];
    u64 my = 0;
    #pragma unroll
    for (int rr = 0; rr < 32; ++rr) {
      u64 m = __ballot(xv[rr] > 0.f);
      if (lane == rr) my = m;
    }
    if (lane < 32) xb[im][w * 32 + lane] = my;
  }
  __syncthreads();

  // ---- stage B: conv1 via PAIR-LUT (+BN threshold) + OR-pool -> s2p ----
  // One 12-bit lookup covers both horizontal windows of the pool pair.
  {
    const int c = lane & 31, h = lane >> 5;    // pooled col, row-half
    const u32 sa0 = (c == 0) ? 0u : (u32)(2 * c - 1);
    const u32 msk = (c == 0) ? 7u : 15u;
    const u32 sft = (c == 0) ? 1u : 0u;
    const u32 tj12 = ((c == 0) ? 0u : ((c == 31) ? 2u : 1u)) << 12;
    #pragma unroll
    for (int p = 0; p < 8; ++p) {
      const int pr = w * 16 + h * 8 + p;
      const int i0 = 2 * pr;
      u64 r0 = (i0 > 0) ? xb[im][i0 - 1] : 0ull;
      u64 r1 = xb[im][i0];
      u64 r2 = xb[im][i0 + 1];
      u64 r3 = (i0 + 2 < 64) ? xb[im][i0 + 2] : 0ull;
      u32 acc = 0;
      #pragma unroll
      for (int a = 0; a < 2; ++a) {
        u64 ra = a ? r1 : r0, rb = a ? r2 : r1, rc = a ? r3 : r2;
        const int i = i0 + a;
        const u32 ti12 = ((i == 0) ? 0u : ((i == 63) ? 6u : 3u)) << 12;
        u32 e0 = ((u32)(ra >> sa0) & msk) << sft;
        u32 e1 = ((u32)(rb >> sa0) & msk) << sft;
        u32 e2 = ((u32)(rc >> sa0) & msk) << sft;
        acc |= slut[ti12 + tj12 + (e0 | (e1 << 4) | (e2 << 8))];
      }
      s2p[im][pr + 1][c + 1] = (u8)acc;
    }
  }
  __syncthreads();

  // ---- preload fcw for this wave's 16 channels (consumed in stage D);
  //      stage C's ~1300 VALU instructions hide the load latency ----
  float fw0[16], fw1[16];
  #pragma unroll
  for (int cc = 0; cc < 16; ++cc) {
    const int f = ((16 * w + cc) << 6) + lane;
    fw0[cc] = fcw[f];
    fw1[cc] = fcw[2048 + f];
  }

  // ---- stage C: conv2 via popcount + int threshold + OR-pool -> s3p ----
  // Each lane: one pooled-output PAIR (2 pooled cols) = 8 windows x 16 ch.
  // Channel-OUTER (unroll 1): 5 SGPR consts per iter, 8-window inner unrolled.
  {
    const int idx = w * 64 + lane;            // 0..127
    const int pi = idx >> 3, pjp = idx & 7;   // pooled row, pooled col-pair
    const int bo = 4 * pjp;                   // byte offset in padded row (4-aligned)
    const u32* rp0 = (const u32*)&s2p[im][2 * pi + 0][bo];
    const u32* rp1 = (const u32*)&s2p[im][2 * pi + 1][bo];
    const u32* rp2 = (const u32*)&s2p[im][2 * pi + 2][bo];
    const u32* rp3 = (const u32*)&s2p[im][2 * pi + 3][bo];
    u32 rl[4], rh[4];
    rl[0] = rp0[0]; rh[0] = rp0[1];
    rl[1] = rp1[0]; rh[1] = rp1[1];
    rl[2] = rp2[0]; rh[2] = rp2[1];
    rl[3] = rp3[0]; rh[3] = rp3[1];

    u32 d0[8], d1[8], d2[8]; int pc[8]; u32 cw[8];
    #pragma unroll
    for (int k = 0; k < 8; ++k) {
      const int o = k >> 2, a = (k >> 1) & 1, bb = k & 1;
      const int sh = 8 * (2 * o + bb);
      d0[k] = __builtin_amdgcn_alignbit(rh[a],     rl[a],     sh) & 0xFFFFFFu;
      d1[k] = __builtin_amdgcn_alignbit(rh[a + 1], rl[a + 1], sh) & 0xFFFFFFu;
      d2[k] = __builtin_amdgcn_alignbit(rh[a + 2], rl[a + 2], sh) & 0xFFFFFFu;
      pc[k] = __popc(d0[k]) + __popc(d1[k]) + __popc(d2[k]);
      cw[k] = 0u;
    }

    #pragma unroll 1
    for (int ch = 15; ch >= 0; --ch) {
      const u32 m0 = cs->p2r[ch][0];
      const u32 m1 = cs->p2r[ch][1];
      const u32 m2 = cs->p2r[ch][2];
      const int nlo = -cs->lo2[ch];
      const u32 rng = cs->rng2[ch];
      #pragma unroll
      for (int k = 0; k < 8; ++k) {
        int ps = __popc(d0[k] & m0) + __popc(d1[k] & m1) + __popc(d2[k] & m2);
        u32 t = (u32)(2 * ps - pc[k] + nlo);
        cw[k] = cw[k] + cw[k] + ((t <= rng) ? 1u : 0u);
      }
    }
    s3p[im][pi + 1][2 * pjp + 1] = (u16)(cw[0] | cw[1] | cw[2] | cw[3]);
    s3p[im][pi + 1][2 * pjp + 2] = (u16)(cw[4] | cw[5] | cw[6] | cw[7]);
  }
  __syncthreads();

  // ---- stage D: conv3 + BN/ReLU/pool (exact fp) + FC; wave w: ch 16w..16w+15 ----
  float l0 = 0.f, l1 = 0.f;
  {
    const int pi = lane >> 3, pj = lane & 7;
    const u32* p0 = (const u32*)(&s3p[im][2 * pi + 0][2 * pj]);
    const u32* p1 = (const u32*)(&s3p[im][2 * pi + 1][2 * pj]);
    const u32* p2 = (const u32*)(&s3p[im][2 * pi + 2][2 * pj]);
    const u32* p3 = (const u32*)(&s3p[im][2 * pi + 3][2 * pj]);
    const u64 rr0 = (u64)p0[0] | ((u64)p0[1] << 32);
    const u64 rr1 = (u64)p1[0] | ((u64)p1[1] << 32);
    const u64 rr2 = (u64)p2[0] | ((u64)p2[1] << 32);
    const u64 rr3 = (u64)p3[0] | ((u64)p3[1] << 32);

    u64 q0a, q1a, q0b, q1b, q0c, q1c, q0d, q1d;
    u32 q2a, q2b, q2c, q2d;
    int pca, pcb, pcc, pcd;
    {
      u64 ta, tb, tc;
      ta = rr0;       tb = rr1;       tc = rr2;
      q0a = (ta & 0xFFFFFFFFFFFFull) | ((tb & 0xFFFFull) << 48);
      q1a = ((tb >> 16) & 0xFFFFFFFFull) | ((tc & 0xFFFFFFFFull) << 32);
      q2a = (u32)((tc >> 32) & 0xFFFFull);
      pca = __popcll(q0a) + __popcll(q1a) + __popc(q2a);
      ta = rr0 >> 16; tb = rr1 >> 16; tc = rr2 >> 16;
      q0b = (ta & 0xFFFFFFFFFFFFull) | ((tb & 0xFFFFull) << 48);
      q1b = ((tb >> 16) & 0xFFFFFFFFull) | ((tc & 0xFFFFFFFFull) << 32);
      q2b = (u32)((tc >> 32) & 0xFFFFull);
      pcb = __popcll(q0b) + __popcll(q1b) + __popc(q2b);
      ta = rr1;       tb = rr2;       tc = rr3;
      q0c = (ta & 0xFFFFFFFFFFFFull) | ((tb & 0xFFFFull) << 48);
      q1c = ((tb >> 16) & 0xFFFFFFFFull) | ((tc & 0xFFFFFFFFull) << 32);
      q2c = (u32)((tc >> 32) & 0xFFFFull);
      pcc = __popcll(q0c) + __popcll(q1c) + __popc(q2c);
      ta = rr1 >> 16; tb = rr2 >> 16; tc = rr3 >> 16;
      q0d = (ta & 0xFFFFFFFFFFFFull) | ((tb & 0xFFFFull) << 48);
      q1d = ((tb >> 16) & 0xFFFFFFFFull) | ((tc & 0xFFFFFFFFull) << 32);
      q2d = (u32)((tc >> 32) & 0xFFFFull);
      pcd = __popcll(q0d) + __popcll(q1d) + __popc(q2d);
    }

    #pragma unroll 2
    for (int cc = 0; cc < 16; ++cc) {
      const int c = 16 * w + cc;
      const u64 m0 = cs->q3m0[c], m1 = cs->q3m1[c];
      const u32 m2 = cs->q3m2[c];
      int t0 = 2 * (__popcll(q0a & m0) + __popcll(q1a & m1) + __popc(q2a & m2)) - pca;
      int t1 = 2 * (__popcll(q0b & m0) + __popcll(q1b & m1) + __popc(q2b & m2)) - pcb;
      int t2 = 2 * (__popcll(q0c & m0) + __popcll(q1c & m1) + __popc(q2c & m2)) - pcc;
      int t3 = 2 * (__popcll(q0d & m0) + __popcll(q1d & m1) + __popc(q2d & m2)) - pcd;
      int smax = max(max(t0, t1), max(t2, t3));
      int smin = min(min(t0, t1), min(t2, t3));
      float inv = cs->inv3[c];
      int sel = (inv > 0.f) ? smax : smin;
      float y   = __fadd_rn((float)sel, cs->b3v[c]);
      float bn  = __fadd_rn(__fmul_rn(y, inv), cs->A3[c]);
      float val = fmaxf(bn, 0.f);
      l0 = fmaf(val, fw0[cc], l0);
      l1 = fmaf(val, fw1[cc], l1);
    }
  }

  // ---- reduce: per-wave shuffle, cross-wave via LDS, softmax ----
  #pragma unroll
  for (int d = 32; d >= 1; d >>= 1) {
    l0 += __shfl_xor(l0, d, 64);
    l1 += __shfl_xor(l1, d, 64);
  }
  if (lane == 0) { red[im][w][0] = l0; red[im][w][1] = l1; }
  __syncthreads();
  if ((tid & 127) == 0 && img < B) {
    float a0 = red[im][0][0] + red[im][1][0] + cs->fcb[0];
    float a1 = red[im][0][1] + red[im][1][1] + cs->fcb[1];
    float mm = fmaxf(a0, a1);
    float e0 = expf(a0 - mm), e1 = expf(a1 - mm);
    float sden = e0 + e1;
    out[(size_t)img * 2]     = e0 / sden;
    out[(size_t)img * 2 + 1] = e1 / sden;
  }
}

extern "C" void kernel_launch(void* const* d_in, const int* in_sizes, int n_in,
                              void* d_out, int out_size, void* d_ws, size_t ws_size,
                              hipStream_t stream) {
  const float* x   = (const float*)d_in[0];
  const float* w1  = (const float*)d_in[1];
  const float* b1  = (const float*)d_in[2];
  const float* g1  = (const float*)d_in[3];
  const float* be1 = (const float*)d_in[4];
  const float* m1  = (const float*)d_in[5];
  const float* v1  = (const float*)d_in[6];
  const float* w2  = (const float*)d_in[7];
  const float* b2  = (const float*)d_in[8];
  const float* g2  = (const float*)d_in[9];
  const float* be2 = (const float*)d_in[10];
  const float* m2  = (const float*)d_in[11];
  const float* v2  = (const float*)d_in[12];
  const float* w3  = (const float*)d_in[13];
  const float* b3  = (const float*)d_in[14];
  const float* g3  = (const float*)d_in[15];
  const float* be3 = (const float*)d_in[16];
  const float* m3  = (const float*)d_in[17];
  const float* v3  = (const float*)d_in[18];
  const float* fcw = (const float*)d_in[19];
  const float* fcb = (const float*)d_in[20];

  int B = in_sizes[0] / 4096;  // 64*64 per image
  Consts* cs = (Consts*)d_ws;

  prep_kernel<<<145, 256, 0, stream>>>(w1, b1, g1, be1, m1, v1,
                                       w2, b2, g2, be2, m2, v2,
                                       w3, b3, g3, be3, m3, v3, fcb, cs);
  int nblk = (B + 1) / 2;
  main_kernel<<<nblk, 256, 0, stream>>>(x, fcw, cs, (float*)d_out, B);
}

// Round 17
// 64.119 us; speedup vs baseline: 1.1564x; 1.0524x over previous
//
#include <hip/hip_runtime.h>
#include <stdint.h>

#define EPS 1e-5f
typedef unsigned long long u64;
typedef unsigned int u32;
typedef unsigned short u16;
typedef unsigned char u8;

// Precomputed constants living in d_ws, produced by prep_kernel each launch.
struct Consts {
  u32 p2r[16][4];   // conv2 +weight row masks: [ch][row r] = 24 bits (col*8+ci), [3]=pad
  u64 q3m0[32];     // conv3 +weight masks, taps 0..3 (bit t*16+ci)
  u64 q3m1[32];     // conv3 taps 4..7
  u32 q3m2[32];     // conv3 tap 8 (16 bits)
  int lo2[16];      // layer2: bit = (u32)(2ps-pc-lo2) <= rng2
  u32 rng2[16];
  float inv3[32];   // layer3 BN scale
  float A3[32];     // layer3 BN offset (beta - mean*inv)
  float b3v[32];    // conv3 bias
  float fcb[2];
  u8  lut[9 * 512]; // layer1: [borderType][pattern] -> 8 thresholded bits
};
static_assert(sizeof(Consts) == 6024, "layout");

// grid: block 0 = masks/thresholds; blocks 1..18 = 256 LUT entries each.
__global__ void prep_kernel(
    const float* __restrict__ w1, const float* __restrict__ b1,
    const float* __restrict__ g1, const float* __restrict__ be1,
    const float* __restrict__ m1, const float* __restrict__ v1,
    const float* __restrict__ w2, const float* __restrict__ b2,
    const float* __restrict__ g2, const float* __restrict__ be2,
    const float* __restrict__ m2, const float* __restrict__ v2,
    const float* __restrict__ w3, const float* __restrict__ b3,
    const float* __restrict__ g3, const float* __restrict__ be3,
    const float* __restrict__ m3, const float* __restrict__ v3,
    const float* __restrict__ fcb, Consts* __restrict__ out)
{
  int tid = threadIdx.x;

  if (blockIdx.x == 0) {
    // ---- layer 2: weight row masks + integer threshold range ----
    if (tid < 16) {
      int c = tid;
      u32 rm[3] = {0u, 0u, 0u};
      for (int ci = 0; ci < 8; ++ci)
        for (int t = 0; t < 9; ++t) {
          float w = w2[(c * 8 + ci) * 9 + t];
          if (w > 0.f) rm[t / 3] |= 1u << ((t % 3) * 8 + ci);
        }
      out->p2r[c][0] = rm[0]; out->p2r[c][1] = rm[1];
      out->p2r[c][2] = rm[2]; out->p2r[c][3] = 0u;
      float inv = __fdiv_rn(g2[c], __fsqrt_rn(__fadd_rn(v2[c], EPS)));
      float A   = __fsub_rn(be2[c], __fmul_rn(m2[c], inv));
      int lo = 1000, hi = -1000;
      for (int s = -72; s <= 72; ++s) {
        float y  = __fadd_rn((float)s, b2[c]);
        float bn = __fadd_rn(__fmul_rn(y, inv), A);
        if (bn > 0.f) { if (s < lo) lo = s; if (s > hi) hi = s; }
      }
      out->lo2[c] = lo; out->rng2[c] = (u32)(hi - lo);
    }
    // ---- layer 3: weight masks + BN params ----
    if (tid < 32) {
      int c = tid;
      u64 q0 = 0, q1 = 0; u32 q2 = 0;
      for (int ci = 0; ci < 16; ++ci)
        for (int t = 0; t < 9; ++t) {
          float w = w3[(c * 16 + ci) * 9 + t];
          if (w > 0.f) {
            if (t < 4)      q0 |= 1ull << (t * 16 + ci);
            else if (t < 8) q1 |= 1ull << ((t - 4) * 16 + ci);
            else            q2 |= 1u << ci;
          }
        }
      out->q3m0[c] = q0; out->q3m1[c] = q1; out->q3m2[c] = q2;
      float inv = __fdiv_rn(g3[c], __fsqrt_rn(__fadd_rn(v3[c], EPS)));
      out->inv3[c] = inv;
      out->A3[c]   = __fsub_rn(be3[c], __fmul_rn(m3[c], inv));
      out->b3v[c]  = b3[c];
    }
    if (tid < 2) out->fcb[tid] = fcb[tid];
    return;
  }

  // ---- layer 1 LUT: one entry per thread ----
  __shared__ float inv1s[8], A1s[8];
  __shared__ int   sw1[8][9];
  if (tid < 8) {
    int c = tid;
    float inv = __fdiv_rn(g1[c], __fsqrt_rn(__fadd_rn(v1[c], EPS)));
    inv1s[c] = inv;
    A1s[c]   = __fsub_rn(be1[c], __fmul_rn(m1[c], inv));
    for (int t = 0; t < 9; ++t) sw1[c][t] = (w1[c * 9 + t] > 0.f) ? 1 : -1;
  }
  __syncthreads();
  int e = (blockIdx.x - 1) * 256 + tid;  // 18*256 = 4608 entries
  int type = e >> 9, pat = e & 511;
  int ty = type / 3, tx = type % 3; // 0: low-edge OOB, 2: high-edge OOB, 1: interior
  u8 byte = 0;
  for (int c = 0; c < 8; ++c) {
    int s = 0;
    for (int t = 0; t < 9; ++t) {
      int dr = t / 3, dc = t % 3;
      bool valid = !((ty == 0 && dr == 0) || (ty == 2 && dr == 2) ||
                     (tx == 0 && dc == 0) || (tx == 2 && dc == 2));
      if (!valid) continue;
      s += ((pat >> t) & 1) ? sw1[c][t] : -sw1[c][t];
    }
    float y  = __fadd_rn((float)s, b1[c]);
    float bn = __fadd_rn(__fmul_rn(y, inv1s[c]), A1s[c]);
    if (bn > 0.f) byte |= (u8)(1u << c);
  }
  out->lut[e] = byte;
}

__launch_bounds__(256, 4)
__global__ void main_kernel(const float* __restrict__ x, const float* __restrict__ fcw,
                            const Consts* __restrict__ cs, float* __restrict__ out, int B)
{
  __shared__ __align__(16) u8  slut[9 * 512];
  __shared__ __align__(16) u64 xb[2][64];       // per-image row bitmasks
  __shared__ __align__(16) u8  s2p[2][34][36];  // pooled layer1 bits (8ch/byte), zero border
  __shared__ __align__(16) u16 s3p[2][18][18];  // pooled layer2 bits (16ch/u16), zero border
  __shared__ float red[2][2][2];

  const int tid = threadIdx.x;
  const int wv = tid >> 6, lane = tid & 63;
  const int im = wv >> 1, w = wv & 1;           // image slot, wave-within-image
  const int img = blockIdx.x * 2 + im;

  // shared LUT copy (u64-vectorized; cs->lut is 8B-aligned) + zero intermediates
  for (int i = tid; i < 576; i += 256) ((u64*)slut)[i] = ((const u64*)cs->lut)[i];
  for (int i = tid; i < 612; i += 256) ((u32*)s2p)[i] = 0;
  for (int i = tid; i < 324; i += 256) ((u32*)s3p)[i] = 0;

  // ---- stage A: prefetch all 32 x-values, then ballot chain (pure VALU) ----
  if (img < B) {
    const float* xp = x + (size_t)img * 4096 + (size_t)w * 2048;
    float xv[32];
    #pragma unroll
    for (int rr = 0; rr < 32; ++rr) xv[rr] = xp[rr * 64 + lane];
    u64 my = 0;
    #pragma unroll
    for (int rr = 0; rr < 32; ++rr) {
      u64 m = __ballot(xv[rr] > 0.f);
      if (lane == rr) my = m;
    }
    if (lane < 32) xb[im][w * 32 + lane] = my;
  }
  __syncthreads();

  // ---- stage B: conv1 via LUT (+BN threshold) + OR-pool -> s2p ----
  // De-diverged column handling: uniform per-lane shift/mask constants.
  {
    const int c = lane & 31, h = lane >> 5;
    const int j0 = 2 * c;
    const u32 sa0  = (c == 0) ? 0u : (u32)(j0 - 1);
    const u32 msk0 = (c == 0) ? 3u : 7u;
    const u32 sft0 = (c == 0) ? 1u : 0u;
    const u32 base0 = ((c == 0) ? 0u : 1u) << 9;   // tj0 << 9
    const u32 base1 = ((c == 31) ? 2u : 1u) << 9;  // tj1 << 9
    #pragma unroll
    for (int p = 0; p < 8; ++p) {
      const int pr = w * 16 + h * 8 + p;
      const int i0 = 2 * pr;
      u64 r0 = (i0 > 0) ? xb[im][i0 - 1] : 0ull;
      u64 r1 = xb[im][i0];
      u64 r2 = xb[im][i0 + 1];
      u64 r3 = (i0 + 2 < 64) ? xb[im][i0 + 2] : 0ull;
      u32 acc = 0;
      #pragma unroll
      for (int a = 0; a < 2; ++a) {
        u64 ra = a ? r1 : r0, rb = a ? r2 : r1, rc = a ? r3 : r2;
        const int i = i0 + a;
        const u32 ti9 = ((i == 0) ? 0u : ((i == 63) ? 6u : 3u)) << 9;
        u32 ea = ((u32)(ra >> sa0) & msk0) << sft0;
        u32 eb = ((u32)(rb >> sa0) & msk0) << sft0;
        u32 ec = ((u32)(rc >> sa0) & msk0) << sft0;
        acc |= slut[ti9 + base0 + (ea | (eb << 3) | (ec << 6))];
        u32 fa = (u32)(ra >> j0) & 7u;
        u32 fb = (u32)(rb >> j0) & 7u;
        u32 fc = (u32)(rc >> j0) & 7u;
        acc |= slut[ti9 + base1 + (fa | (fb << 3) | (fc << 6))];
      }
      s2p[im][pr + 1][c + 1] = (u8)acc;
    }
  }
  __syncthreads();

  // ---- preload fcw for this wave's 16 channels (consumed in stage D);
  //      stage C's ~1300 VALU instructions hide the load latency ----
  float fw0[16], fw1[16];
  #pragma unroll
  for (int cc = 0; cc < 16; ++cc) {
    const int f = ((16 * w + cc) << 6) + lane;
    fw0[cc] = fcw[f];
    fw1[cc] = fcw[2048 + f];
  }

  // ---- stage C: conv2 via popcount + int threshold + OR-pool -> s3p ----
  // Each lane: one pooled-output PAIR (2 pooled cols) = 8 windows x 16 ch.
  // Channel-OUTER (unroll 1): 5 SGPR consts per iter, 8-window inner unrolled.
  {
    const int idx = w * 64 + lane;            // 0..127
    const int pi = idx >> 3, pjp = idx & 7;   // pooled row, pooled col-pair
    const int bo = 4 * pjp;                   // byte offset in padded row (4-aligned)
    const u32* rp0 = (const u32*)&s2p[im][2 * pi + 0][bo];
    const u32* rp1 = (const u32*)&s2p[im][2 * pi + 1][bo];
    const u32* rp2 = (const u32*)&s2p[im][2 * pi + 2][bo];
    const u32* rp3 = (const u32*)&s2p[im][2 * pi + 3][bo];
    u32 rl[4], rh[4];
    rl[0] = rp0[0]; rh[0] = rp0[1];
    rl[1] = rp1[0]; rh[1] = rp1[1];
    rl[2] = rp2[0]; rh[2] = rp2[1];
    rl[3] = rp3[0]; rh[3] = rp3[1];

    u32 d0[8], d1[8], d2[8]; int pc[8]; u32 cw[8];
    #pragma unroll
    for (int k = 0; k < 8; ++k) {
      const int o = k >> 2, a = (k >> 1) & 1, bb = k & 1;
      const int sh = 8 * (2 * o + bb);
      d0[k] = __builtin_amdgcn_alignbit(rh[a],     rl[a],     sh) & 0xFFFFFFu;
      d1[k] = __builtin_amdgcn_alignbit(rh[a + 1], rl[a + 1], sh) & 0xFFFFFFu;
      d2[k] = __builtin_amdgcn_alignbit(rh[a + 2], rl[a + 2], sh) & 0xFFFFFFu;
      pc[k] = __popc(d0[k]) + __popc(d1[k]) + __popc(d2[k]);
      cw[k] = 0u;
    }

    #pragma unroll 1
    for (int ch = 15; ch >= 0; --ch) {
      const u32 m0 = cs->p2r[ch][0];
      const u32 m1 = cs->p2r[ch][1];
      const u32 m2 = cs->p2r[ch][2];
      const int nlo = -cs->lo2[ch];
      const u32 rng = cs->rng2[ch];
      #pragma unroll
      for (int k = 0; k < 8; ++k) {
        int ps = __popc(d0[k] & m0) + __popc(d1[k] & m1) + __popc(d2[k] & m2);
        u32 t = (u32)(2 * ps - pc[k] + nlo);
        cw[k] = cw[k] + cw[k] + ((t <= rng) ? 1u : 0u);
      }
    }
    s3p[im][pi + 1][2 * pjp + 1] = (u16)(cw[0] | cw[1] | cw[2] | cw[3]);
    s3p[im][pi + 1][2 * pjp + 2] = (u16)(cw[4] | cw[5] | cw[6] | cw[7]);
  }
  __syncthreads();

  // ---- stage D: conv3 + BN/ReLU/pool (exact fp) + FC; wave w: ch 16w..16w+15 ----
  float l0 = 0.f, l1 = 0.f;
  {
    const int pi = lane >> 3, pj = lane & 7;
    const u32* p0 = (const u32*)(&s3p[im][2 * pi + 0][2 * pj]);
    const u32* p1 = (const u32*)(&s3p[im][2 * pi + 1][2 * pj]);
    const u32* p2 = (const u32*)(&s3p[im][2 * pi + 2][2 * pj]);
    const u32* p3 = (const u32*)(&s3p[im][2 * pi + 3][2 * pj]);
    const u64 rr0 = (u64)p0[0] | ((u64)p0[1] << 32);
    const u64 rr1 = (u64)p1[0] | ((u64)p1[1] << 32);
    const u64 rr2 = (u64)p2[0] | ((u64)p2[1] << 32);
    const u64 rr3 = (u64)p3[0] | ((u64)p3[1] << 32);

    u64 q0a, q1a, q0b, q1b, q0c, q1c, q0d, q1d;
    u32 q2a, q2b, q2c, q2d;
    int pca, pcb, pcc, pcd;
    {
      u64 ta, tb, tc;
      ta = rr0;       tb = rr1;       tc = rr2;
      q0a = (ta & 0xFFFFFFFFFFFFull) | ((tb & 0xFFFFull) << 48);
      q1a = ((tb >> 16) & 0xFFFFFFFFull) | ((tc & 0xFFFFFFFFull) << 32);
      q2a = (u32)((tc >> 32) & 0xFFFFull);
      pca = __popcll(q0a) + __popcll(q1a) + __popc(q2a);
      ta = rr0 >> 16; tb = rr1 >> 16; tc = rr2 >> 16;
      q0b = (ta & 0xFFFFFFFFFFFFull) | ((tb & 0xFFFFull) << 48);
      q1b = ((tb >> 16) & 0xFFFFFFFFull) | ((tc & 0xFFFFFFFFull) << 32);
      q2b = (u32)((tc >> 32) & 0xFFFFull);
      pcb = __popcll(q0b) + __popcll(q1b) + __popc(q2b);
      ta = rr1;       tb = rr2;       tc = rr3;
      q0c = (ta & 0xFFFFFFFFFFFFull) | ((tb & 0xFFFFull) << 48);
      q1c = ((tb >> 16) & 0xFFFFFFFFull) | ((tc & 0xFFFFFFFFull) << 32);
      q2c = (u32)((tc >> 32) & 0xFFFFull);
      pcc = __popcll(q0c) + __popcll(q1c) + __popc(q2c);
      ta = rr1 >> 16; tb = rr2 >> 16; tc = rr3 >> 16;
      q0d = (ta & 0xFFFFFFFFFFFFull) | ((tb & 0xFFFFull) << 48);
      q1d = ((tb >> 16) & 0xFFFFFFFFull) | ((tc & 0xFFFFFFFFull) << 32);
      q2d = (u32)((tc >> 32) & 0xFFFFull);
      pcd = __popcll(q0d) + __popcll(q1d) + __popc(q2d);
    }

    #pragma unroll 2
    for (int cc = 0; cc < 16; ++cc) {
      const int c = 16 * w + cc;
      const u64 m0 = cs->q3m0[c], m1 = cs->q3m1[c];
      const u32 m2 = cs->q3m2[c];
      int t0 = 2 * (__popcll(q0a & m0) + __popcll(q1a & m1) + __popc(q2a & m2)) - pca;
      int t1 = 2 * (__popcll(q0b & m0) + __popcll(q1b & m1) + __popc(q2b & m2)) - pcb;
      int t2 = 2 * (__popcll(q0c & m0) + __popcll(q1c & m1) + __popc(q2c & m2)) - pcc;
      int t3 = 2 * (__popcll(q0d & m0) + __popcll(q1d & m1) + __popc(q2d & m2)) - pcd;
      int smax = max(max(t0, t1), max(t2, t3));
      int smin = min(min(t0, t1), min(t2, t3));
      float inv = cs->inv3[c];
      int sel = (inv > 0.f) ? smax : smin;
      float y   = __fadd_rn((float)sel, cs->b3v[c]);
      float bn  = __fadd_rn(__fmul_rn(y, inv), cs->A3[c]);
      float val = fmaxf(bn, 0.f);
      l0 = fmaf(val, fw0[cc], l0);
      l1 = fmaf(val, fw1[cc], l1);
    }
  }

  // ---- reduce: per-wave shuffle, cross-wave via LDS, softmax ----
  #pragma unroll
  for (int d = 32; d >= 1; d >>= 1) {
    l0 += __shfl_xor(l0, d, 64);
    l1 += __shfl_xor(l1, d, 64);
  }
  if (lane == 0) { red[im][w][0] = l0; red[im][w][1] = l1; }
  __syncthreads();
  if ((tid & 127) == 0 && img < B) {
    float a0 = red[im][0][0] + red[im][1][0] + cs->fcb[0];
    float a1 = red[im][0][1] + red[im][1][1] + cs->fcb[1];
    float mm = fmaxf(a0, a1);
    float e0 = expf(a0 - mm), e1 = expf(a1 - mm);
    float sden = e0 + e1;
    out[(size_t)img * 2]     = e0 / sden;
    out[(size_t)img * 2 + 1] = e1 / sden;
  }
}

extern "C" void kernel_launch(void* const* d_in, const int* in_sizes, int n_in,
                              void* d_out, int out_size, void* d_ws, size_t ws_size,
                              hipStream_t stream) {
  const float* x   = (const float*)d_in[0];
  const float* w1  = (const float*)d_in[1];
  const float* b1  = (const float*)d_in[2];
  const float* g1  = (const float*)d_in[3];
  const float* be1 = (const float*)d_in[4];
  const float* m1  = (const float*)d_in[5];
  const float* v1  = (const float*)d_in[6];
  const float* w2  = (const float*)d_in[7];
  const float* b2  = (const float*)d_in[8];
  const float* g2  = (const float*)d_in[9];
  const float* be2 = (const float*)d_in[10];
  const float* m2  = (const float*)d_in[11];
  const float* v2  = (const float*)d_in[12];
  const float* w3  = (const float*)d_in[13];
  const float* b3  = (const float*)d_in[14];
  const float* g3  = (const float*)d_in[15];
  const float* be3 = (const float*)d_in[16];
  const float* m3  = (const float*)d_in[17];
  const float* v3  = (const float*)d_in[18];
  const float* fcw = (const float*)d_in[19];
  const float* fcb = (const float*)d_in[20];

  int B = in_sizes[0] / 4096;  // 64*64 per image
  Consts* cs = (Consts*)d_ws;

  prep_kernel<<<19, 256, 0, stream>>>(w1, b1, g1, be1, m1, v1,
                                      w2, b2, g2, be2, m2, v2,
                                      w3, b3, g3, be3, m3, v3, fcb, cs);
  int nblk = (B + 1) / 2;
  main_kernel<<<nblk, 256, 0, stream>>>(x, fcw, cs, (float*)d_out, B);
}